// Round 1
// baseline (488.060 us; speedup 1.0000x reference)
//
#include <hip/hip_runtime.h>

// ClusteredAttention: B=2, L=2048, H=8 heads, D=64, fp32.
//   Kp[b,m,:] = sum_v key[b,m,v,:]
//   scores[b,l,h,m] = <q[b,l,h,:], Kp[b,m,:]> * (1/8)
//   A = softmax over m;  out[b,l,h,:] = sum_m A * value[b,m,h,:]
// Softmax without max-subtraction: |scaled score| <~ 20 << 88 (fp32 exp safe),
// so single-pass p=exp(s/8), accumulate sum(p) and sum(p*V), divide at end.

#define BB 2
#define LL 2048
#define HH 8
#define DD 64
#define TQ 64          // query rows per block
#define NKSLICE 4      // waves per block; each wave owns L/NKSLICE = 512 keys
#define KPW 16         // keys staged per wave per iteration
#define NITER 32       // 512 / 16
#define LDSPAD 68      // padded row stride (floats); 272 B, 16B-aligned

__global__ void pool_keys_kernel(const float* __restrict__ key,
                                 float* __restrict__ kp) {
    int idx = blockIdx.x * blockDim.x + threadIdx.x;   // over B*L*D
    if (idx >= BB * LL * DD) return;
    int d  = idx & (DD - 1);
    int bm = idx >> 6;                                  // b*L + m
    const float* kbase = key + ((size_t)bm * HH) * DD + d;
    float s = 0.f;
#pragma unroll
    for (int v = 0; v < HH; ++v) s += kbase[v * DD];
    kp[idx] = s;
}

__global__ __launch_bounds__(256, 2)
void attn_kernel(const float* __restrict__ query,
                 const float* __restrict__ kp,
                 const float* __restrict__ value,
                 float* __restrict__ out) {
    const float SCALE = 0.125f;   // 1/sqrt(64)

    int bid = blockIdx.x;          // [0, B*H*(L/TQ)) = [0,512)
    int qt  = bid & 31;            // query tile (L/TQ = 32)
    int bh  = bid >> 5;            // b*H + h
    int h   = bh & 7;
    int b   = bh >> 3;

    int tid = threadIdx.x;
    int row = tid & 63;            // query row within tile (one thread per row)
    int wv  = tid >> 6;            // wave id = key-slice id

    __shared__ __align__(16) float Ks[TQ][LDSPAD];  // 64 staged key rows
    __shared__ __align__(16) float Vs[TQ][LDSPAD];
    __shared__ float Lred[TQ];

    // ---- load this thread's query row into registers ----
    int lq = qt * TQ + row;
    const float4* qp = (const float4*)(query +
        (((size_t)(b * LL + lq)) * HH + h) * DD);
    float qreg[DD];
#pragma unroll
    for (int c = 0; c < 16; ++c) {
        float4 t = qp[c];
        qreg[4*c+0] = t.x; qreg[4*c+1] = t.y;
        qreg[4*c+2] = t.z; qreg[4*c+3] = t.w;
    }

    float O[DD];
#pragma unroll
    for (int i = 0; i < DD; ++i) O[i] = 0.f;
    float lsum = 0.f;

    // ---- main loop: 32 iterations; each stages 64 key rows (16 per wave) ----
    for (int it = 0; it < NITER; ++it) {
        __syncthreads();   // previous iteration's readers done before overwrite
        // cooperative staging: 64 rows x 64 floats for K and V
#pragma unroll
        for (int k = 0; k < 4; ++k) {
            int f = tid + k * 256;          // [0, 1024) float4 slots
            int r = f >> 4;                 // staged row [0,64)
            int c = f & 15;                 // float4 column [0,16)
            int g = r >> 4;                 // owning wave / key slice
            int j = r & 15;
            int m = g * 512 + it * KPW + j; // global key index
            float4 kv = *(const float4*)(kp + ((size_t)(b * LL + m)) * DD + 4 * c);
            ((float4*)&Ks[r][0])[c] = kv;
            float4 vv = *(const float4*)(value +
                (((size_t)(b * LL + m)) * HH + h) * DD + 4 * c);
            ((float4*)&Vs[r][0])[c] = vv;
        }
        __syncthreads();

        // this wave consumes staged rows [wv*16, wv*16+16)
        for (int j = 0; j < KPW; ++j) {
            int r = wv * KPW + j;
            float a0 = 0.f, a1 = 0.f, a2 = 0.f, a3 = 0.f;
#pragma unroll
            for (int c = 0; c < 16; ++c) {
                float4 kk = ((const float4*)&Ks[r][0])[c];   // wave-uniform broadcast
                a0 += qreg[4*c+0] * kk.x;
                a1 += qreg[4*c+1] * kk.y;
                a2 += qreg[4*c+2] * kk.z;
                a3 += qreg[4*c+3] * kk.w;
            }
            float s = (a0 + a1) + (a2 + a3);
            float p = __expf(s * SCALE);
            lsum += p;
#pragma unroll
            for (int c = 0; c < 16; ++c) {
                float4 vv = ((const float4*)&Vs[r][0])[c];   // broadcast
                O[4*c+0] += p * vv.x;
                O[4*c+1] += p * vv.y;
                O[4*c+2] += p * vv.z;
                O[4*c+3] += p * vv.w;
            }
        }
    }

    // ---- combine the 4 key-slices per query row (reuse Ks as O buffer) ----
    __syncthreads();
    if (wv == 0) {
#pragma unroll
        for (int c = 0; c < 16; ++c) {
            float4 t;
            t.x = O[4*c+0]; t.y = O[4*c+1]; t.z = O[4*c+2]; t.w = O[4*c+3];
            ((float4*)&Ks[row][0])[c] = t;
        }
        Lred[row] = lsum;
    }
    __syncthreads();
    for (int w = 1; w < NKSLICE; ++w) {
        if (wv == w) {
#pragma unroll
            for (int i = 0; i < DD; ++i) Ks[row][i] += O[i];
            Lred[row] += lsum;
        }
        __syncthreads();
    }

    // ---- normalize + write: thread (row, wv) writes dims [wv*16, wv*16+16) ----
    float inv = 1.0f / Lred[row];
    size_t obase = (((size_t)(b * LL + qt * TQ + row)) * HH + h) * DD + wv * 16;
#pragma unroll
    for (int c = 0; c < 4; ++c) {
        float4 t = ((const float4*)&Ks[row][0])[wv * 4 + c];
        t.x *= inv; t.y *= inv; t.z *= inv; t.w *= inv;
        *(float4*)(out + obase + 4 * c) = t;
    }
}

extern "C" void kernel_launch(void* const* d_in, const int* in_sizes, int n_in,
                              void* d_out, int out_size, void* d_ws, size_t ws_size,
                              hipStream_t stream) {
    const float* query = (const float*)d_in[0];
    const float* key   = (const float*)d_in[1];
    const float* value = (const float*)d_in[2];
    // d_in[3] = label_arr (int64) — mathematically dead in the reference.
    float* out = (float*)d_out;
    float* kp  = (float*)d_ws;   // B*L*D fp32 = 2 MB pooled keys

    int npool = BB * LL * DD;
    pool_keys_kernel<<<(npool + 255) / 256, 256, 0, stream>>>(key, kp);

    int nblocks = BB * HH * (LL / TQ);   // 512
    attn_kernel<<<nblocks, 256, 0, stream>>>(query, kp, value, out);
}

// Round 3
// 139.711 us; speedup vs baseline: 3.4934x; 3.4934x over previous
//
#include <hip/hip_runtime.h>

// ClusteredAttention via bf16 MFMA (fp32 accumulate). B=2, L=2048, H=8, D=64.
//   Kp[b,m,:] = sum_v key[b,m,v,:]            (prepass -> bf16 kb, 512 KiB ws)
//   S^T[key][qrow] = Kp . Q   (mfma 32x32x16, A=K, B=Q)
//   P = exp(S/8)   (no max-subtraction: |s/8| <~ 20 << 88, fp32 exp safe)
//   O = P . V      (mfma, A=P from own lane regs, B=Vt bf16 transposed+permuted)
//   out = O / rowsum(P)
//
// WS DISCIPLINE (round-2 lesson): vt for all 16 (b,h) is 4 MiB and overflowed
// ws_size, corrupting the harness's pristine input copies (first call passed,
// post-timing calls failed deterministically). Now vt is materialized for only
// `nbh` heads at a time, nbh chosen from ws_size; vtrans->attn chunks are
// stream-serialized, identical work every call.

#define BB 2
#define LL 2048
#define HH 8
#define DD 64

typedef __attribute__((ext_vector_type(8)))  short  short8;   // 8 bf16 = 4 VGPR
typedef __attribute__((ext_vector_type(16))) float  float16v; // 32x32 C/D frag

static __device__ inline unsigned short f2bf(float x) {       // RNE
    union { float f; unsigned u; } v; v.f = x;
    unsigned r = v.u + 0x7FFF + ((v.u >> 16) & 1);
    return (unsigned short)(r >> 16);
}
static __device__ inline unsigned pk_bf2(float x, float y) {
    return (unsigned)f2bf(x) | ((unsigned)f2bf(y) << 16);
}

// ---------------- prepass 1: pooled keys -> bf16 kb[b][m][s] ----------------
__global__ void pool_kernel(const float* __restrict__ key,
                            unsigned short* __restrict__ kb) {
    int idx = blockIdx.x * blockDim.x + threadIdx.x;   // B*L*D = 262144
    int d  = idx & (DD - 1);
    int bm = idx >> 6;
    const float* kbase = key + ((size_t)bm * HH) * DD + d;
    float s = 0.f;
#pragma unroll
    for (int v = 0; v < HH; ++v) s += kbase[v * DD];
    kb[idx] = f2bf(s);
}

// --- prepass 2 (chunked): vt[bhl][s][m'] bf16, m' = m with bits 2,3 swapped --
// LDS-staged transpose: coalesced float4 global reads, conflict-free column
// reads (wave-uniform m-group), short8 stores.
__global__ void vtrans_kernel(const float* __restrict__ value,
                              unsigned short* __restrict__ vt, int bh0) {
    int blk = blockIdx.x;            // nbh * 32 m-tiles
    int mt  = blk & 31;
    int bhl = blk >> 5;
    int bh  = bh0 + bhl;
    int h = bh & 7, b = bh >> 3;
    int m0 = mt * 64;
    int tid = threadIdx.x;

    __shared__ __align__(16) float Vl[64][68];   // pitch 68: float4-aligned

    #pragma unroll
    for (int k = 0; k < 4; ++k) {
        int f = tid + k * 256;       // 64 rows x 16 float4
        int r = f >> 4;
        int c = (f & 15) * 4;
        float4 t = *(const float4*)(value +
            (((size_t)(b * LL + m0 + r)) * HH + h) * DD + c);
        *(float4*)&Vl[r][c] = t;
    }
    __syncthreads();

    int s  = tid & 63;               // lane-varying: 2 lanes/bank (free)
    int mg = tid >> 6;               // wave-uniform m-group
    union { short8 v; unsigned short u[8]; } o0, o1;
    #pragma unroll
    for (int j = 0; j < 16; ++j) {
        int p   = mg * 16 + j;
        int src = (p & ~12) | ((p & 4) << 1) | ((p & 8) >> 1);  // swap bits 2,3
        float x = Vl[src][s];
        if (j < 8) o0.u[j] = f2bf(x); else o1.u[j - 8] = f2bf(x);
    }
    unsigned short* dst = vt + ((size_t)(bhl * DD + s)) * LL + m0 + mg * 16;
    *(short8*)dst       = o0.v;
    *(short8*)(dst + 8) = o1.v;
}

// ------------------------------- main kernel --------------------------------
template<int NW>
__global__ __launch_bounds__(NW * 64)
void attn_kernel_t(const float* __restrict__ query,
                   const unsigned short* __restrict__ kb,
                   const unsigned short* __restrict__ vt,
                   float* __restrict__ out, int bh0) {
    const float SCALE = 0.125f;
    constexpr int SLICE = LL / NW;   // keys per wave
    constexpr int NIT   = SLICE / 32;

    int bid = blockIdx.x;            // nbh * 64 q-tiles
    int qt  = bid & 63;
    int bhl = bid >> 6;
    int bh  = bh0 + bhl;
    int h = bh & 7, b = bh >> 3;

    int tid  = threadIdx.x;
    int lane = tid & 63;
    int wv   = tid >> 6;
    int ln   = lane & 31;
    int half = lane >> 5;

    __shared__ float O4[NW][32][DD];
    __shared__ float lsumL[NW][64];
    __shared__ float invL[32];

    // Q B-frags: B[k=s][n=qrow]; lane: n=ln, k = ks*16 + half*8 + j
    short8 qf[4];
    const float* qbase = query + (((size_t)(b * LL + qt * 32 + ln)) * HH + h) * DD;
#pragma unroll
    for (int ks = 0; ks < 4; ++ks) {
        const float4* qp = (const float4*)(qbase + ks * 16 + half * 8);
        float4 t0 = qp[0], t1 = qp[1];
        union { short8 v; unsigned u[4]; } uq;
        uq.u[0] = pk_bf2(t0.x, t0.y);
        uq.u[1] = pk_bf2(t0.z, t0.w);
        uq.u[2] = pk_bf2(t1.x, t1.y);
        uq.u[3] = pk_bf2(t1.z, t1.w);
        qf[ks] = uq.v;
    }

    float16v o0, o1;
#pragma unroll
    for (int i = 0; i < 16; ++i) { o0[i] = 0.f; o1[i] = 0.f; }
    float lsum = 0.f;

    const unsigned short* kbb = kb + ((size_t)b * LL) * DD;
    const unsigned short* vt0 = vt + ((size_t)(bhl * DD)) * LL;
    const unsigned short* vr0 = vt0 + (size_t)ln * LL;
    const unsigned short* vr1 = vt0 + (size_t)(32 + ln) * LL;

    for (int it = 0; it < NIT; ++it) {
        int mk = wv * SLICE + it * 32;

        // K A-frags: A[m=key][k=s]; lane: m = mk+ln, k = ks*16 + half*8 + j
        const unsigned short* krow = kbb + (size_t)(mk + ln) * DD + half * 8;
        float16v sacc;
#pragma unroll
        for (int i = 0; i < 16; ++i) sacc[i] = 0.f;
#pragma unroll
        for (int ks = 0; ks < 4; ++ks) {
            short8 kf = *(const short8*)(krow + ks * 16);
            sacc = __builtin_amdgcn_mfma_f32_32x32x16_bf16(kf, qf[ks], sacc, 0, 0, 0);
        }

        // exp + rowsum + cheap round-half-up bf16 pack via v_perm (1 perm + 2
        // adds per dword vs ~8 ops for RNE; bias is zero-mean half-ULP)
        float p[16];
        float ls = 0.f;
#pragma unroll
        for (int r = 0; r < 16; ++r) { p[r] = __expf(sacc[r] * SCALE); ls += p[r]; }
        lsum += ls;

        union { short8 v[2]; unsigned u[8]; } pu;
#pragma unroll
        for (int i = 0; i < 8; ++i) {
            union { float f; unsigned u; } a, c;
            a.f = p[2 * i]; c.f = p[2 * i + 1];
            pu.u[i] = __builtin_amdgcn_perm(c.u + 0x8000u, a.u + 0x8000u, 0x07060302u);
        }

        // V B-frags: B[k=key][n=scol]; permuted key order matches P slots
#pragma unroll
        for (int t = 0; t < 2; ++t) {
            short8 vf0 = *(const short8*)(vr0 + mk + t * 16 + half * 8);
            short8 vf1 = *(const short8*)(vr1 + mk + t * 16 + half * 8);
            o0 = __builtin_amdgcn_mfma_f32_32x32x16_bf16(pu.v[t], vf0, o0, 0, 0, 0);
            o1 = __builtin_amdgcn_mfma_f32_32x32x16_bf16(pu.v[t], vf1, o1, 0, 0, 0);
        }
    }

    // ---- epilogue: combine NW key-slice waves ----
    lsumL[wv][lane] = lsum;
#pragma unroll
    for (int r = 0; r < 16; ++r) {
        int row = (r & 3) + 8 * (r >> 2) + 4 * half;
        O4[wv][row][ln]      = o0[r];
        O4[wv][row][32 + ln] = o1[r];
    }
    __syncthreads();

    if (tid < 32) {
        float s = 0.f;
#pragma unroll
        for (int w = 0; w < NW; ++w) s += lsumL[w][tid] + lsumL[w][tid + 32];
        invL[tid] = 1.0f / s;
    }
    __syncthreads();

    if (tid < 256) {
        int qrow = tid >> 3;
        int c8   = (tid & 7) * 8;
        float inv = invL[qrow];
        float buf[8];
#pragma unroll
        for (int i = 0; i < 8; ++i) {
            float acc = 0.f;
#pragma unroll
            for (int w = 0; w < NW; ++w) acc += O4[w][qrow][c8 + i];
            buf[i] = acc * inv;
        }
        float* ob = out + (((size_t)(b * LL + qt * 32 + qrow)) * HH + h) * DD + c8;
        *(float4*)(ob)     = make_float4(buf[0], buf[1], buf[2], buf[3]);
        *(float4*)(ob + 4) = make_float4(buf[4], buf[5], buf[6], buf[7]);
    }
}

extern "C" void kernel_launch(void* const* d_in, const int* in_sizes, int n_in,
                              void* d_out, int out_size, void* d_ws, size_t ws_size,
                              hipStream_t stream) {
    const float* query = (const float*)d_in[0];
    const float* key   = (const float*)d_in[1];
    const float* value = (const float*)d_in[2];
    float* out = (float*)d_out;

    unsigned short* kb = (unsigned short*)d_ws;                       // 512 KiB
    unsigned short* vt = (unsigned short*)((char*)d_ws + 512 * 1024);

    // vt needs DD*LL*2 = 256 KiB per (b,h). Pick largest pow2 chunk that fits.
    size_t avail = (ws_size > (size_t)(512 * 1024)) ? ws_size - 512 * 1024 : 0;
    int nbh = (int)(avail / ((size_t)DD * LL * 2));
    if (nbh >= 16) nbh = 16; else if (nbh >= 8) nbh = 8;
    else if (nbh >= 4) nbh = 4; else if (nbh >= 2) nbh = 2; else nbh = 1;

    pool_kernel<<<(BB * LL * DD) / 256, 256, 0, stream>>>(key, kb);

    for (int bh0 = 0; bh0 < BB * HH; bh0 += nbh) {
        vtrans_kernel<<<nbh * 32, 256, 0, stream>>>(value, vt, bh0);
        if (nbh > 4) {
            // enough blocks for >=2 blocks/CU with 4-wave blocks
            attn_kernel_t<4><<<nbh * 64, 256, 0, stream>>>(query, kb, vt, out, bh0);
        } else {
            // few blocks: 8-wave blocks to keep >=2 waves/SIMD
            attn_kernel_t<8><<<nbh * 64, 512, 0, stream>>>(query, kb, vt, out, bh0);
        }
    }
}

// Round 4
// 105.397 us; speedup vs baseline: 4.6307x; 1.3256x over previous
//
#include <hip/hip_runtime.h>

// ClusteredAttention via bf16 MFMA, fragment-swizzled operands. B=2,L=2048,H=8,D=64.
//   Kp[b,m,:] = sum_v key[b,m,v,:]        (pool prepass -> kswz, frag-linear bf16)
//   S^T = Kp . Q      (mfma 32x32x16, A=K, B=Q; C-layout col = q-row)
//   P = exp(S/8)      (scale folded into Q pack; no max-sub: |s/8| << 88)
//   O = P . V         (A=P from own lane regs, B=V from vswz, frag-linear bf16)
//   out = O / rowsum(P)
//
// ROUND-3 LESSON: loading MFMA fragments directly from row-major global = 32-64
// cache lines per load instruction -> L1 transaction-rate bound (73us for ~4us
// of pipe work, MfmaUtil 9%). Fix: prepasses store K/V in EXACTLY the per-lane
// fragment order, so every hot-loop load is one coalesced 1KB dwordx4. The m-
// permutation of the P A-frag layout is folded into vswz's indexing.
//
// WS: kswz 512KiB + nbh*256KiB vswz, nbh sized from ws_size (round-2 lesson).

#define BB 2
#define LL 2048
#define HH 8
#define DD 64

typedef __attribute__((ext_vector_type(8)))  short  short8;   // 8 bf16 = 4 VGPR
typedef __attribute__((ext_vector_type(16))) float  float16v; // 32x32 C/D frag

static __device__ inline unsigned short f2bf(float x) {       // RNE
    union { float f; unsigned u; } v; v.f = x;
    unsigned r = v.u + 0x7FFF + ((v.u >> 16) & 1);
    return (unsigned short)(r >> 16);
}
static __device__ inline unsigned pk_bf2(float x, float y) {
    return (unsigned)f2bf(x) | ((unsigned)f2bf(y) << 16);
}

// --------- prepass 1: pooled keys -> kswz, fragment-linear bf16 -------------
// kswz chunk ((b*64+T)*4+ks) is 1KB: lane=(half*32+ln) holds 16B = row T*32+ln,
// cols ks*16+half*8 .. +8  (exactly the A-frag read pattern of the hot loop).
__global__ void pool_kernel(const float* __restrict__ key,
                            unsigned short* __restrict__ kswz) {
    int c  = blockIdx.x * blockDim.x + threadIdx.x;  // B*L*8 = 32768 chunks/8
    int r  = c >> 3;                  // b*L + m
    int ck = c & 7;
    int ks = ck >> 1, hf = ck & 1;
    int b = r >> 11, ml = r & 2047;
    int T = ml >> 5, ln = ml & 31;

    const float* base = key + ((size_t)r * HH) * DD + ks * 16 + hf * 8;
    float s[8];
#pragma unroll
    for (int j = 0; j < 8; ++j) s[j] = 0.f;
#pragma unroll
    for (int v = 0; v < HH; ++v) {
        float4 f0 = *(const float4*)(base + v * DD);
        float4 f1 = *(const float4*)(base + v * DD + 4);
        s[0] += f0.x; s[1] += f0.y; s[2] += f0.z; s[3] += f0.w;
        s[4] += f1.x; s[5] += f1.y; s[6] += f1.z; s[7] += f1.w;
    }
    union { short8 v; unsigned u[4]; } o;
#pragma unroll
    for (int i = 0; i < 4; ++i) o.u[i] = pk_bf2(s[2 * i], s[2 * i + 1]);
    *(short8*)(kswz + ((((size_t)b * 64 + T) * 4 + ks) * 512)
                    + (hf * 32 + ln) * 8) = o.v;
}

// --------- prepass 2 (chunked): V -> vswz, fragment-linear bf16 -------------
// vswz chunk ((bhl*64+T)*4 + t*2 + vh) is 1KB: lane=(half*32+ln) holds 16B =
// V[m = T*32 + perm(t,half,jj)][s = vh*32+ln], jj=0..7, where
// perm = (r&3)+8*(r>>2)+4*half with r=t*8+jj  (P A-frag slot -> key mapping).
__global__ void vswz_kernel(const float* __restrict__ value,
                            unsigned short* __restrict__ vswz, int bh0) {
    int blk = blockIdx.x;             // nbh * 32 blocks (64 keys each)
    int mt  = blk & 31;
    int bhl = blk >> 5;
    int bh  = bh0 + bhl;
    int h = bh & 7, b = bh >> 3;
    int m0 = mt * 64;
    int tid = threadIdx.x;

    __shared__ __align__(16) float Vl[64][68];

#pragma unroll
    for (int k = 0; k < 4; ++k) {
        int f = tid + k * 256;        // 64 rows x 16 float4
        int r = f >> 4;
        int cc = (f & 15) * 4;
        float4 t = *(const float4*)(value +
            (((size_t)(b * LL + m0 + r)) * HH + h) * DD + cc);
        *(float4*)&Vl[r][cc] = t;
    }
    __syncthreads();

#pragma unroll
    for (int k = 0; k < 2; ++k) {
        int c    = tid + k * 256;     // 512 chunks: Tl(2) x t(2) x vh(2) x lane(64)
        int Tl   = c >> 8;
        int t    = (c >> 7) & 1;
        int vh   = (c >> 6) & 1;
        int lane = c & 63;
        int ln = lane & 31, half = lane >> 5;
        union { short8 v; unsigned short u[8]; } o;
#pragma unroll
        for (int jj = 0; jj < 8; ++jj) {
            int r2  = t * 8 + jj;
            int key = (r2 & 3) + 8 * (r2 >> 2) + 4 * half;
            o.u[jj] = f2bf(Vl[Tl * 32 + key][vh * 32 + ln]);
        }
        *(short8*)(vswz + ((((size_t)bhl * 64 + (mt * 2 + Tl)) * 4 + t * 2 + vh) * 512)
                        + lane * 8) = o.v;
    }
}

// ------------------------------- main kernel --------------------------------
__global__ __launch_bounds__(512, 4)
void attn_kernel(const float* __restrict__ query,
                 const unsigned short* __restrict__ kswz,
                 const unsigned short* __restrict__ vswz,
                 float* __restrict__ out, int bh0) {
    constexpr int NIT = 8;            // 8 waves x 8 tiles x 32 keys = 2048

    int bid = blockIdx.x;             // nbh * 64 q-tiles
    int qt  = bid & 63;
    int bhl = bid >> 6;
    int bh  = bh0 + bhl;
    int h = bh & 7, b = bh >> 3;

    int tid  = threadIdx.x;
    int lane = tid & 63;
    int wv   = tid >> 6;              // 8 key-slices of 256 keys
    int ln   = lane & 31;
    int half = lane >> 5;

    __shared__ float O4[4][32][DD];   // 32KB (two-stage combine, <=64KB limit)
    __shared__ float lsumL[4][64];
    __shared__ float invL[32];

    // Q B-frags, pre-scaled by 1/8 (exact in bf16): B[k=s][n=qrow=ln]
    short8 qf[4];
    const float* qbase = query + (((size_t)(b * LL + qt * 32 + ln)) * HH + h) * DD;
#pragma unroll
    for (int ks = 0; ks < 4; ++ks) {
        const float4* qp = (const float4*)(qbase + ks * 16 + half * 8);
        float4 t0 = qp[0], t1 = qp[1];
        union { short8 v; unsigned u[4]; } uq;
        uq.u[0] = pk_bf2(t0.x * 0.125f, t0.y * 0.125f);
        uq.u[1] = pk_bf2(t0.z * 0.125f, t0.w * 0.125f);
        uq.u[2] = pk_bf2(t1.x * 0.125f, t1.y * 0.125f);
        uq.u[3] = pk_bf2(t1.z * 0.125f, t1.w * 0.125f);
        qf[ks] = uq.v;
    }

    const unsigned short* kp0 = kswz + (((size_t)b * 64 + wv * 8) * 4) * 512
                                     + (size_t)lane * 8;
    const unsigned short* vp0 = vswz + (((size_t)bhl * 64 + wv * 8) * 4) * 512
                                     + (size_t)lane * 8;

    float16v o0, o1;
#pragma unroll
    for (int i = 0; i < 16; ++i) { o0[i] = 0.f; o1[i] = 0.f; }
    float lsum = 0.f;

    short8 kf[4];
#pragma unroll
    for (int ks = 0; ks < 4; ++ks) kf[ks] = *(const short8*)(kp0 + ks * 512);

#pragma unroll
    for (int it = 0; it < NIT; ++it) {
        // V frags for this tile (independent of S; issue early)
        short8 vf[4];
#pragma unroll
        for (int u = 0; u < 4; ++u)
            vf[u] = *(const short8*)(vp0 + it * 2048 + u * 512);

        // S^T = K.Q
        float16v sacc;
#pragma unroll
        for (int i = 0; i < 16; ++i) sacc[i] = 0.f;
#pragma unroll
        for (int ks = 0; ks < 4; ++ks)
            sacc = __builtin_amdgcn_mfma_f32_32x32x16_bf16(kf[ks], qf[ks], sacc, 0, 0, 0);

        // prefetch next K tile
        short8 kn[4];
        if (it + 1 < NIT) {
#pragma unroll
            for (int ks = 0; ks < 4; ++ks)
                kn[ks] = *(const short8*)(kp0 + (it + 1) * 2048 + ks * 512);
        }

        // exp + rowsum + fused bf16 pack (round-half-up via v_perm)
        union { short8 v[2]; unsigned u[8]; } pu;
#pragma unroll
        for (int i = 0; i < 8; ++i) {
            union { float f; unsigned u; } e0, e1;
            e0.f = __expf(sacc[2 * i]);
            e1.f = __expf(sacc[2 * i + 1]);
            lsum += e0.f + e1.f;
            pu.u[i] = __builtin_amdgcn_perm(e1.u + 0x8000u, e0.u + 0x8000u, 0x07060302u);
        }

        // O += P.V
#pragma unroll
        for (int t = 0; t < 2; ++t) {
            o0 = __builtin_amdgcn_mfma_f32_32x32x16_bf16(pu.v[t], vf[t * 2 + 0], o0, 0, 0, 0);
            o1 = __builtin_amdgcn_mfma_f32_32x32x16_bf16(pu.v[t], vf[t * 2 + 1], o1, 0, 0, 0);
        }

        if (it + 1 < NIT) {
#pragma unroll
            for (int ks = 0; ks < 4; ++ks) kf[ks] = kn[ks];
        }
    }

    // ---- two-stage epilogue: waves 0-3 write, waves 4-7 add, then combine ----
    if (wv < 4) {
        lsumL[wv][lane] = lsum;
#pragma unroll
        for (int r = 0; r < 16; ++r) {
            int row = (r & 3) + 8 * (r >> 2) + 4 * half;
            O4[wv][row][ln]      = o0[r];
            O4[wv][row][32 + ln] = o1[r];
        }
    }
    __syncthreads();
    if (wv >= 4) {
        lsumL[wv - 4][lane] += lsum;
#pragma unroll
        for (int r = 0; r < 16; ++r) {
            int row = (r & 3) + 8 * (r >> 2) + 4 * half;
            O4[wv - 4][row][ln]      += o0[r];
            O4[wv - 4][row][32 + ln] += o1[r];
        }
    }
    __syncthreads();

    if (tid < 32) {
        float s = 0.f;
#pragma unroll
        for (int w = 0; w < 4; ++w) s += lsumL[w][tid] + lsumL[w][tid + 32];
        invL[tid] = 1.0f / s;
    }
    __syncthreads();

    // 512 threads: each writes 4 floats of one output row
    int qrow = tid >> 4;
    int c4   = (tid & 15) * 4;
    float inv = invL[qrow];
    float4 r;
    r.x = (O4[0][qrow][c4 + 0] + O4[1][qrow][c4 + 0] + O4[2][qrow][c4 + 0] + O4[3][qrow][c4 + 0]) * inv;
    r.y = (O4[0][qrow][c4 + 1] + O4[1][qrow][c4 + 1] + O4[2][qrow][c4 + 1] + O4[3][qrow][c4 + 1]) * inv;
    r.z = (O4[0][qrow][c4 + 2] + O4[1][qrow][c4 + 2] + O4[2][qrow][c4 + 2] + O4[3][qrow][c4 + 2]) * inv;
    r.w = (O4[0][qrow][c4 + 3] + O4[1][qrow][c4 + 3] + O4[2][qrow][c4 + 3] + O4[3][qrow][c4 + 3]) * inv;
    *(float4*)(out + (((size_t)(b * LL + qt * 32 + qrow)) * HH + h) * DD + c4) = r;
}

extern "C" void kernel_launch(void* const* d_in, const int* in_sizes, int n_in,
                              void* d_out, int out_size, void* d_ws, size_t ws_size,
                              hipStream_t stream) {
    const float* query = (const float*)d_in[0];
    const float* key   = (const float*)d_in[1];
    const float* value = (const float*)d_in[2];
    float* out = (float*)d_out;

    unsigned short* kswz = (unsigned short*)d_ws;                       // 512 KiB
    unsigned short* vswz = (unsigned short*)((char*)d_ws + 512 * 1024);

    // vswz needs 256 KiB per (b,h); pick largest pow2 chunk that fits ws_size.
    size_t avail = (ws_size > (size_t)(512 * 1024)) ? ws_size - 512 * 1024 : 0;
    int nbh = (int)(avail / ((size_t)DD * LL * 2));
    if (nbh >= 16) nbh = 16; else if (nbh >= 8) nbh = 8;
    else if (nbh >= 4) nbh = 4; else if (nbh >= 2) nbh = 2; else nbh = 1;

    pool_kernel<<<(BB * LL * 8) / 256, 256, 0, stream>>>(key, kswz);

    for (int bh0 = 0; bh0 < BB * HH; bh0 += nbh) {
        vswz_kernel<<<nbh * 32, 256, 0, stream>>>(value, vswz, bh0);
        attn_kernel<<<nbh * 64, 512, 0, stream>>>(query, kswz, vswz, out, bh0);
    }
}